// Round 4
// baseline (552.291 us; speedup 1.0000x reference)
//
#include <hip/hip_runtime.h>
#include <stdint.h>

#define BB 512
#define TT 1024
#define KK 48
#define PF 8

typedef float v2f __attribute__((ext_vector_type(2)));

// mask may arrive as 1-byte bools (raw numpy) or as 4-byte words.
__device__ __forceinline__ int mask_at(const void* m, int idx, bool bytes) {
    return bytes ? (int)(((const uint8_t*)m)[idx] != 0)
                 : (int)(((const int*)m)[idx] != 0);
}

__device__ __forceinline__ float bcast(float v, int lane) {
    return __int_as_float(__builtin_amdgcn_readlane(__float_as_int(v), lane));
}

__device__ __forceinline__ v2f mk2(float x, float y) { v2f r; r.x = x; r.y = y; return r; }

// ------------- forward algorithm, TWO rows per wave -------------------
// R7/R8: R6's structure (2-row interleave, LDS broadcast, packed FMA) was
// right but the asm memory-clobber fences forced the backend to drain
// lgkmcnt(0) right after each 12x ds_read_b128 block -> the ~130cy LDS
// roundtrip sat naked on the chain twice per pair-step (884 cyc/pair-step
// measured, VALUBusy 11.8%). Fix: NO fences. Ordering is already guaranteed:
//  - plX[lane]=p (store) vs float4 loads of plX may alias -> compiler keeps
//    program order;
//  - DS pipe is in-order per wave -> reads see the write, no barrier needed
//    (single wave per block, wave-synchronous LDS).
// The compiler then places s_waitcnt before FIRST USE (next X-step), so the
// roundtrip hides under the other row's ~100cy of compute.
// Both rows run 1024 padded steps; state captured in-flight at t==len
// (mask is prefix). Renorm schedule replicates the R4 main+tail pattern
// exactly -> bit-identical floats (absmax 0.0 at R6).
// (R8 resubmission: R7 bench failed on container acquire, kernel never ran.)
__global__ __launch_bounds__(64, 1) void crf_fwd(
    const float* __restrict__ em, const int* __restrict__ tags,
    const void* __restrict__ mask, const float* __restrict__ trans,
    const float* __restrict__ start, const float* __restrict__ endt,
    float* __restrict__ ws)
{
    __shared__ __align__(16) float plA[64];
    __shared__ __align__(16) float plB[64];

    const int bid = blockIdx.x;
    const int bA = 2 * bid, bB = 2 * bid + 1;
    const int lane = threadIdx.x;
    const bool active = lane < KK;
    const int j = active ? lane : KK - 1;   // clamp for safe loads

    const bool mb = (*(const int*)mask) == 0x01010101;

    // sequence lengths = popcount of prefix masks
    int cntA = 0, cntB = 0;
    for (int t = lane; t < TT; t += 64) {
        cntA += mask_at(mask, bA * TT + t, mb);
        cntB += mask_at(mask, bB * TT + t, mb);
    }
    #pragma unroll
    for (int off = 32; off >= 1; off >>= 1) {
        cntA += __shfl_xor(cntA, off);
        cntB += __shfl_xor(cntB, off);
    }
    const int lenA = __builtin_amdgcn_readfirstlane(cntA);
    const int lenB = __builtin_amdgcn_readfirstlane(cntB);

    // E packed as pairs along k: etr2[i] = (E[2i][j], E[2i+1][j])
    v2f etr2[KK / 2];
    #pragma unroll
    for (int i = 0; i < KK / 2; ++i) {
        float e0 = active ? __expf(trans[(2 * i)     * KK + j]) : 0.0f;
        float e1 = active ? __expf(trans[(2 * i + 1) * KK + j]) : 0.0f;
        v2f t2 = mk2(e0, e1);
        asm volatile("" : "+v"(t2));
        etr2[i] = t2;
    }

    const float* embA = em + (size_t)bA * TT * KK;
    const float* embB = em + (size_t)bB * TT * KK;

    // init: p = exp(S_0 - c), c = S_0[0]
    float s0A = start[j] + embA[j];
    float s0B = start[j] + embB[j];
    float cAc = bcast(s0A, 0);
    float cBc = bcast(s0B, 0);
    float pA = active ? __expf(s0A - cAc) : 0.0f;
    float pB = active ? __expf(s0B - cBc) : 0.0f;

    const float* plAf = plA;
    const float* plBf = plB;
    float4 rA[12], rB[12];
    plA[lane] = pA;
    plB[lane] = pB;
    #pragma unroll
    for (int i = 0; i < 12; ++i) rA[i] = *(const float4*)(plAf + 4 * i);
    #pragma unroll
    for (int i = 0; i < 12; ++i) rB[i] = *(const float4*)(plBf + 4 * i);

    // emission prefetch pipelines
    float pipeA[PF], pipeB[PF];
    #pragma unroll
    for (int d = 0; d < PF; ++d) {
        pipeA[d] = embA[(size_t)(1 + d) * KK + j];
        pipeB[d] = embB[(size_t)(1 + d) * KK + j];
    }

    float pcapA = 0.f, pcapB = 0.f, ccapA = 0.f, ccapB = 0.f;

    for (int t = 1; t + PF <= TT + 1; t += PF) {
        // replicate R4 main/tail renorm split: tail blocks renorm every step
        const bool tailA = (t + PF > lenA);
        const bool tailB = (t + PF > lenB);
        #pragma unroll
        for (int d = 0; d < PF; ++d) {
            const int tc = t + d;
            const bool rn = (d == 0) || (d == 4);
            // capture pre-step state at t == len (final state of the row)
            if (tc == lenA) { pcapA = pA; ccapA = cAc; }
            if (tc == lenB) { pcapB = pB; ccapB = cBc; }
            // ---------------- row A step ----------------
            {
                float eA = __expf(pipeA[d]);
                { int tt = tc + PF; tt = tt < TT ? tt : TT - 1;
                  pipeA[d] = embA[(size_t)tt * KK + j]; }
                const bool renorm = rn || tailA;
                float s0 = rA[0].x;
                float scale = eA;
                if (renorm) scale *= __builtin_amdgcn_rcpf(s0);
                v2f Q01 = mk2(rA[0].x, rA[0].y) * etr2[0];
                v2f Q23 = mk2(rA[0].z, rA[0].w) * etr2[1];
                #pragma unroll
                for (int i = 1; i < 12; ++i) {
                    Q01 = __builtin_elementwise_fma(mk2(rA[i].x, rA[i].y), etr2[2 * i],     Q01);
                    Q23 = __builtin_elementwise_fma(mk2(rA[i].z, rA[i].w), etr2[2 * i + 1], Q23);
                }
                if (renorm) cAc += __logf(s0);
                float qs = (Q01.x + Q01.y) + (Q23.x + Q23.y);
                pA = qs * scale;
                plA[lane] = pA;                 // publish
                #pragma unroll
                for (int i = 0; i < 12; ++i) rA[i] = *(const float4*)(plAf + 4 * i);
                // ^ reads issued now; waitcnt lands before next A-step's FMAs,
                //   so the roundtrip flies under row B's compute.
            }
            // ---------------- row B step ----------------
            {
                float eB = __expf(pipeB[d]);
                { int tt = tc + PF; tt = tt < TT ? tt : TT - 1;
                  pipeB[d] = embB[(size_t)tt * KK + j]; }
                const bool renorm = rn || tailB;
                float s0 = rB[0].x;
                float scale = eB;
                if (renorm) scale *= __builtin_amdgcn_rcpf(s0);
                v2f Q01 = mk2(rB[0].x, rB[0].y) * etr2[0];
                v2f Q23 = mk2(rB[0].z, rB[0].w) * etr2[1];
                #pragma unroll
                for (int i = 1; i < 12; ++i) {
                    Q01 = __builtin_elementwise_fma(mk2(rB[i].x, rB[i].y), etr2[2 * i],     Q01);
                    Q23 = __builtin_elementwise_fma(mk2(rB[i].z, rB[i].w), etr2[2 * i + 1], Q23);
                }
                if (renorm) cBc += __logf(s0);
                float qs = (Q01.x + Q01.y) + (Q23.x + Q23.y);
                pB = qs * scale;
                plB[lane] = pB;                 // publish
                #pragma unroll
                for (int i = 0; i < 12; ++i) rB[i] = *(const float4*)(plBf + 4 * i);
            }
        }
    }

    // log_z = c + log(sum_j pcap_j * exp(end_j))
    const float ee = active ? __expf(endt[j]) : 0.0f;
    float vA = pcapA * ee;
    float vB = pcapB * ee;
    #pragma unroll
    for (int off = 32; off >= 1; off >>= 1) {
        vA += __shfl_xor(vA, off);
        vB += __shfl_xor(vB, off);
    }

    // ---- fused gold-path scores (mask is prefix: m[t] == (t < len)) ----
    const int* tgA = tags + bA * TT;
    const int* tgB = tags + bB * TT;
    float sqA = 0.f, sqB = 0.f;
    for (int tt2 = lane; tt2 < TT; tt2 += 64) {
        if (tt2 >= 1 && tt2 < lenA) {
            int tp = tgA[tt2 - 1], tn = tgA[tt2];
            sqA += trans[tp * KK + tn] + embA[(size_t)tt2 * KK + tn];
        }
        if (tt2 >= 1 && tt2 < lenB) {
            int tp = tgB[tt2 - 1], tn = tgB[tt2];
            sqB += trans[tp * KK + tn] + embB[(size_t)tt2 * KK + tn];
        }
    }
    #pragma unroll
    for (int off = 32; off >= 1; off >>= 1) {
        sqA += __shfl_xor(sqA, off);
        sqB += __shfl_xor(sqB, off);
    }

    if (lane == 0) {
        int t0A = tgA[0], t0B = tgB[0];
        ws[bA]      = ccapA + __logf(vA);
        ws[BB + bA] = sqA + start[t0A] + embA[t0A] + endt[tgA[lenA - 1]];
        ws[bB]      = ccapB + __logf(vB);
        ws[BB + bB] = sqB + start[t0B] + embB[t0B] + endt[tgB[lenB - 1]];
    }
}

// ---------------- final mean reduction ----------------
__global__ __launch_bounds__(256) void crf_final(const float* __restrict__ ws,
                                                 float* __restrict__ out)
{
    __shared__ float red[256];
    float s = 0.f;
    for (int b = threadIdx.x; b < BB; b += 256) s += ws[b] - ws[BB + b];
    red[threadIdx.x] = s;
    __syncthreads();
    for (int off = 128; off > 0; off >>= 1) {
        if (threadIdx.x < off) red[threadIdx.x] += red[threadIdx.x + off];
        __syncthreads();
    }
    if (threadIdx.x == 0) out[0] = red[0] / (float)BB;
}

extern "C" void kernel_launch(void* const* d_in, const int* in_sizes, int n_in,
                              void* d_out, int out_size, void* d_ws, size_t ws_size,
                              hipStream_t stream) {
    const float* em    = (const float*)d_in[0];
    const int*   tags  = (const int*)d_in[1];
    const void*  mask  = d_in[2];
    const float* trans = (const float*)d_in[3];
    const float* start = (const float*)d_in[4];
    const float* endt  = (const float*)d_in[5];
    float* ws  = (float*)d_ws;
    float* out = (float*)d_out;

    crf_fwd  <<<BB / 2, 64, 0, stream>>>(em, tags, mask, trans, start, endt, ws);
    crf_final<<<1,      256, 0, stream>>>(ws, out);
}

// Round 5
// 469.813 us; speedup vs baseline: 1.1756x; 1.1756x over previous
//
#include <hip/hip_runtime.h>
#include <stdint.h>

#define BB 512
#define TT 1024
#define KK 48
#define PF 8

typedef float v2f __attribute__((ext_vector_type(2)));
typedef float v4f __attribute__((ext_vector_type(4)));

// mask may arrive as 1-byte bools (raw numpy) or as 4-byte words.
__device__ __forceinline__ int mask_at(const void* m, int idx, bool bytes) {
    return bytes ? (int)(((const uint8_t*)m)[idx] != 0)
                 : (int)(((const int*)m)[idx] != 0);
}

__device__ __forceinline__ float bcast(float v, int lane) {
    return __int_as_float(__builtin_amdgcn_readlane(__float_as_int(v), lane));
}

__device__ __forceinline__ v2f mk2(float x, float y) { v2f r; r.x = x; r.y = y; return r; }

// one uniform-address broadcast read: 4 p-values into a VGPR quad
#define DS_READ(dst, OFFSTR) \
    asm volatile("ds_read_b128 %0, %1 offset:" OFFSTR : "=v"(dst) : "v"(r0))

// A tile at LDS bytes [0,192), B tile at [256,448)
#define RD_A() do { \
    DS_READ(rA[0],  "0");   DS_READ(rA[1],  "16");  DS_READ(rA[2],  "32");  \
    DS_READ(rA[3],  "48");  DS_READ(rA[4],  "64");  DS_READ(rA[5],  "80");  \
    DS_READ(rA[6],  "96");  DS_READ(rA[7],  "112"); DS_READ(rA[8],  "128"); \
    DS_READ(rA[9],  "144"); DS_READ(rA[10], "160"); DS_READ(rA[11], "176"); } while (0)
#define RD_B() do { \
    DS_READ(rB[0],  "256"); DS_READ(rB[1],  "272"); DS_READ(rB[2],  "288"); \
    DS_READ(rB[3],  "304"); DS_READ(rB[4],  "320"); DS_READ(rB[5],  "336"); \
    DS_READ(rB[6],  "352"); DS_READ(rB[7],  "368"); DS_READ(rB[8],  "384"); \
    DS_READ(rB[9],  "400"); DS_READ(rB[10], "416"); DS_READ(rB[11], "432"); } while (0)

// ------------- forward algorithm, TWO rows per wave -------------------
// R9: HIP-source control of the LDS waitcnt placement failed both ways:
//  - R6 (mem-clobber fences): backend drains lgkmcnt(0) right after the
//    reads -> roundtrip naked on chain (884 cyc/pair-step).
//  - R8 (no fences): scheduler sinks the reads to first-use -> roundtrip
//    naked again, worse (1078 cyc/pair-step).
// Fix (T3/T4 discipline, rule #18): inline-asm DS ops + hand-COUNTED
// s_waitcnt lgkmcnt(13) + sched_barrier(0). Per row-step: FMA phase ->
// ds_write_b32 + 12x ds_read_b128 issued; the wait for those 13 lands just
// before the SAME row's next FMA phase, so they fly under the OTHER row's
// phase. Ledger: before each wait, outstanding = own-13(oldest)+other-13;
// lgkmcnt(13) retires exactly the own row's ops. Never drains to 0 in-loop.
// No compiler DS/SMEM ops in the loop -> the lgkm count is exact.
// Math sequence identical to R6 (absmax 0.0): same FMA order, same renorm
// schedule (d==0||d==4, tail blocks every step), capture state at t==len.
__global__ __launch_bounds__(64, 1) void crf_fwd(
    const float* __restrict__ em, const int* __restrict__ tags,
    const void* __restrict__ mask, const float* __restrict__ trans,
    const float* __restrict__ start, const float* __restrict__ endt,
    float* __restrict__ ws)
{
    __shared__ __align__(16) float pl[128];   // [0..63]=row A, [64..127]=row B

    const int bid = blockIdx.x;
    const int bA = 2 * bid, bB = 2 * bid + 1;
    const int lane = threadIdx.x;
    const bool active = lane < KK;
    const int j = active ? lane : KK - 1;   // clamp for safe loads

    const bool mb = (*(const int*)mask) == 0x01010101;

    // sequence lengths = popcount of prefix masks
    int cntA = 0, cntB = 0;
    for (int t = lane; t < TT; t += 64) {
        cntA += mask_at(mask, bA * TT + t, mb);
        cntB += mask_at(mask, bB * TT + t, mb);
    }
    #pragma unroll
    for (int off = 32; off >= 1; off >>= 1) {
        cntA += __shfl_xor(cntA, off);
        cntB += __shfl_xor(cntB, off);
    }
    const int lenA = __builtin_amdgcn_readfirstlane(cntA);
    const int lenB = __builtin_amdgcn_readfirstlane(cntB);

    // E packed as pairs along k: etr2[i] = (E[2i][j], E[2i+1][j])
    v2f etr2[KK / 2];
    #pragma unroll
    for (int i = 0; i < KK / 2; ++i) {
        float e0 = active ? __expf(trans[(2 * i)     * KK + j]) : 0.0f;
        float e1 = active ? __expf(trans[(2 * i + 1) * KK + j]) : 0.0f;
        v2f t2 = mk2(e0, e1);
        asm volatile("" : "+v"(t2));
        etr2[i] = t2;
    }

    const float* embA = em + (size_t)bA * TT * KK;
    const float* embB = em + (size_t)bB * TT * KK;

    // init: p = exp(S_0 - c), c = S_0[0]
    float s0A = start[j] + embA[j];
    float s0B = start[j] + embB[j];
    float cAc = bcast(s0A, 0);
    float cBc = bcast(s0B, 0);
    float pA = active ? __expf(s0A - cAc) : 0.0f;
    float pB = active ? __expf(s0B - cBc) : 0.0f;

    // LDS addresses (generic->LDS offset: shared aperture is 4GB-aligned,
    // low 32 bits are the LDS byte offset)
    uint32_t wAddr = (uint32_t)(uintptr_t)(&pl[lane]);  // A write; B via offset:256
    uint32_t r0    = (uint32_t)(uintptr_t)(&pl[0]);     // uniform read base

    v4f rA[12], rB[12];

    // prologue: issue [wA,12rA][wB,12rB] -> matches steady-state ledger
    asm volatile("ds_write_b32 %0, %1" :: "v"(wAddr), "v"(pA));
    RD_A();
    asm volatile("ds_write_b32 %0, %1 offset:256" :: "v"(wAddr), "v"(pB));
    RD_B();

    // emission prefetch pipelines (vmcnt, independent of lgkm ledger)
    float pipeA[PF], pipeB[PF];
    #pragma unroll
    for (int d = 0; d < PF; ++d) {
        pipeA[d] = embA[(size_t)(1 + d) * KK + j];
        pipeB[d] = embB[(size_t)(1 + d) * KK + j];
    }

    float pcapA = 0.f, pcapB = 0.f, ccapA = 0.f, ccapB = 0.f;

    for (int t = 1; t + PF <= TT + 1; t += PF) {
        // R4 main/tail renorm split: tail blocks renorm every step
        const bool tailA = (t + PF > lenA);
        const bool tailB = (t + PF > lenB);
        #pragma unroll
        for (int d = 0; d < PF; ++d) {
            const int tc = t + d;
            const bool rn = (d == 0) || (d == 4);
            // capture pre-step state at t == len (final state of the row)
            if (tc == lenA) { pcapA = pA; ccapA = cAc; }
            if (tc == lenB) { pcapB = pB; ccapB = cBc; }
            // ---------------- row A step ----------------
            // outstanding: A13(oldest) + B13 -> retire A's 13 only
            asm volatile("s_waitcnt lgkmcnt(13)");
            __builtin_amdgcn_sched_barrier(0);
            {
                float eA = __expf(pipeA[d]);
                { int tt = tc + PF; tt = tt < TT ? tt : TT - 1;
                  pipeA[d] = embA[(size_t)tt * KK + j]; }
                const bool renorm = rn || tailA;
                float s0 = rA[0][0];
                float scale = eA;
                if (renorm) scale *= __builtin_amdgcn_rcpf(s0);
                v2f Q01 = mk2(rA[0][0], rA[0][1]) * etr2[0];
                v2f Q23 = mk2(rA[0][2], rA[0][3]) * etr2[1];
                #pragma unroll
                for (int i = 1; i < 12; ++i) {
                    Q01 = __builtin_elementwise_fma(mk2(rA[i][0], rA[i][1]), etr2[2 * i],     Q01);
                    Q23 = __builtin_elementwise_fma(mk2(rA[i][2], rA[i][3]), etr2[2 * i + 1], Q23);
                }
                if (renorm) cAc += __logf(s0);
                float qs = (Q01.x + Q01.y) + (Q23.x + Q23.y);
                pA = qs * scale;
            }
            asm volatile("ds_write_b32 %0, %1" :: "v"(wAddr), "v"(pA));
            RD_A();   // fly under row B's FMA phase
            // ---------------- row B step ----------------
            // outstanding: B13(oldest) + A13(new) -> retire B's 13 only
            asm volatile("s_waitcnt lgkmcnt(13)");
            __builtin_amdgcn_sched_barrier(0);
            {
                float eB = __expf(pipeB[d]);
                { int tt = tc + PF; tt = tt < TT ? tt : TT - 1;
                  pipeB[d] = embB[(size_t)tt * KK + j]; }
                const bool renorm = rn || tailB;
                float s0 = rB[0][0];
                float scale = eB;
                if (renorm) scale *= __builtin_amdgcn_rcpf(s0);
                v2f Q01 = mk2(rB[0][0], rB[0][1]) * etr2[0];
                v2f Q23 = mk2(rB[0][2], rB[0][3]) * etr2[1];
                #pragma unroll
                for (int i = 1; i < 12; ++i) {
                    Q01 = __builtin_elementwise_fma(mk2(rB[i][0], rB[i][1]), etr2[2 * i],     Q01);
                    Q23 = __builtin_elementwise_fma(mk2(rB[i][2], rB[i][3]), etr2[2 * i + 1], Q23);
                }
                if (renorm) cBc += __logf(s0);
                float qs = (Q01.x + Q01.y) + (Q23.x + Q23.y);
                pB = qs * scale;
            }
            asm volatile("ds_write_b32 %0, %1 offset:256" :: "v"(wAddr), "v"(pB));
            RD_B();   // fly under next A FMA phase
        }
    }
    asm volatile("s_waitcnt lgkmcnt(0)");   // drain before epilogue shuffles

    // log_z = c + log(sum_j pcap_j * exp(end_j))
    const float ee = active ? __expf(endt[j]) : 0.0f;
    float vA = pcapA * ee;
    float vB = pcapB * ee;
    #pragma unroll
    for (int off = 32; off >= 1; off >>= 1) {
        vA += __shfl_xor(vA, off);
        vB += __shfl_xor(vB, off);
    }

    // ---- fused gold-path scores (mask is prefix: m[t] == (t < len)) ----
    const int* tgA = tags + bA * TT;
    const int* tgB = tags + bB * TT;
    float sqA = 0.f, sqB = 0.f;
    for (int tt2 = lane; tt2 < TT; tt2 += 64) {
        if (tt2 >= 1 && tt2 < lenA) {
            int tp = tgA[tt2 - 1], tn = tgA[tt2];
            sqA += trans[tp * KK + tn] + embA[(size_t)tt2 * KK + tn];
        }
        if (tt2 >= 1 && tt2 < lenB) {
            int tp = tgB[tt2 - 1], tn = tgB[tt2];
            sqB += trans[tp * KK + tn] + embB[(size_t)tt2 * KK + tn];
        }
    }
    #pragma unroll
    for (int off = 32; off >= 1; off >>= 1) {
        sqA += __shfl_xor(sqA, off);
        sqB += __shfl_xor(sqB, off);
    }

    if (lane == 0) {
        int t0A = tgA[0], t0B = tgB[0];
        ws[bA]      = ccapA + __logf(vA);
        ws[BB + bA] = sqA + start[t0A] + embA[t0A] + endt[tgA[lenA - 1]];
        ws[bB]      = ccapB + __logf(vB);
        ws[BB + bB] = sqB + start[t0B] + embB[t0B] + endt[tgB[lenB - 1]];
    }
}

// ---------------- final mean reduction ----------------
__global__ __launch_bounds__(256) void crf_final(const float* __restrict__ ws,
                                                 float* __restrict__ out)
{
    __shared__ float red[256];
    float s = 0.f;
    for (int b = threadIdx.x; b < BB; b += 256) s += ws[b] - ws[BB + b];
    red[threadIdx.x] = s;
    __syncthreads();
    for (int off = 128; off > 0; off >>= 1) {
        if (threadIdx.x < off) red[threadIdx.x] += red[threadIdx.x + off];
        __syncthreads();
    }
    if (threadIdx.x == 0) out[0] = red[0] / (float)BB;
}

extern "C" void kernel_launch(void* const* d_in, const int* in_sizes, int n_in,
                              void* d_out, int out_size, void* d_ws, size_t ws_size,
                              hipStream_t stream) {
    const float* em    = (const float*)d_in[0];
    const int*   tags  = (const int*)d_in[1];
    const void*  mask  = d_in[2];
    const float* trans = (const float*)d_in[3];
    const float* start = (const float*)d_in[4];
    const float* endt  = (const float*)d_in[5];
    float* ws  = (float*)d_ws;
    float* out = (float*)d_out;

    crf_fwd  <<<BB / 2, 64, 0, stream>>>(em, tags, mask, trans, start, endt, ws);
    crf_final<<<1,      256, 0, stream>>>(ws, out);
}

// Round 8
// 368.639 us; speedup vs baseline: 1.4982x; 1.2745x over previous
//
#include <hip/hip_runtime.h>
#include <stdint.h>

#define BB 512
#define TT 1024
#define KK 48
#define PF 8

typedef float v2f __attribute__((ext_vector_type(2)));

// mask may arrive as 1-byte bools (raw numpy) or as 4-byte words.
__device__ __forceinline__ int mask_at(const void* m, int idx, bool bytes) {
    return bytes ? (int)(((const uint8_t*)m)[idx] != 0)
                 : (int)(((const int*)m)[idx] != 0);
}

__device__ __forceinline__ float bcast(float v, int lane) {
    return __int_as_float(__builtin_amdgcn_readlane(__float_as_int(v), lane));
}

__device__ __forceinline__ v2f mk2(float x, float y) { v2f r; r.x = x; r.y = y; return r; }

// 4-way cross-group (16-lane rows) sum: xor-16 then xor-32 butterfly.
__device__ __forceinline__ float xred4(float h) {
    h += __shfl_xor(h, 16);
    h += __shfl_xor(h, 32);
    return h;
}

// ------------- forward algorithm, split-K(4x16), one row per wave ---------
// R12: split-K kills the measured plateau (uniform-address broadcast reads
// don't dedup on the LDS return path: 12x ds_read_b128/step = ~300cy of
// pipe occupancy in R5/R6/R9). lane=(g,l): partials for outputs
// {l,l+16,l+32} over inputs {12g..12g+11} (18 pk_fma), cross-group reduce
// via shfl_xor butterfly, lane j (=16g+l) keeps its own output (slot o=g),
// scalar emission+renorm, then 1 ds_write_b32 + 3 ds_read_b128 of the
// lane's 12-float group slice (4 distinct addrs/read -> 16 banks).
// DS ops 13 -> 4 per step.
// IMPLEMENTATION STYLE (R10/R11 post-mortem): both asm-DS variants aborted;
// this version is 100% compiler-managed (plain LDS accesses, standard
// shfl) — the exact style R8 proved correct. Store->load ordering via
// aliasing; single wave per block -> wave-synchronous LDS, no barrier.
// Renorm schedule (d==0||d==4 main, every-step in tail blocks) and the
// t==len pre-step capture replicate R0 exactly; dot products reassociated
// (tolerance-safe, ~1e-6).
__global__ __launch_bounds__(64, 1) void crf_fwd(
    const float* __restrict__ em, const int* __restrict__ tags,
    const void* __restrict__ mask, const float* __restrict__ trans,
    const float* __restrict__ start, const float* __restrict__ endt,
    float* __restrict__ ws)
{
    __shared__ __align__(16) float pl[64];   // 0..47 = p; 48..63 dummy

    const int b = blockIdx.x;
    const int lane = threadIdx.x;
    const int g = lane >> 4;          // input group 0..3
    const int l = lane & 15;
    const bool ownj = lane < KK;      // lane j<48 owns state j
    const int j = ownj ? lane : KK - 1;   // clamp for em loads

    const bool mb = (*(const int*)mask) == 0x01010101;

    // sequence length = popcount of prefix mask
    int cnt = 0;
    for (int t = lane; t < TT; t += 64) cnt += mask_at(mask, b * TT + t, mb);
    #pragma unroll
    for (int off = 32; off >= 1; off >>= 1) cnt += __shfl_xor(cnt, off);
    const int len = cnt;

    // E fragments: etr[mm][o] = (E[12g+2mm][16o+l], E[12g+2mm+1][16o+l])
    // all indices valid for all 64 lanes (i<=47, j<=47)
    v2f etr[6][3];
    #pragma unroll
    for (int mm = 0; mm < 6; ++mm) {
        #pragma unroll
        for (int o = 0; o < 3; ++o) {
            const int i0 = 12 * g + 2 * mm;
            const int jo = 16 * o + l;
            v2f t2 = mk2(__expf(trans[i0 * KK + jo]),
                         __expf(trans[(i0 + 1) * KK + jo]));
            asm volatile("" : "+v"(t2));
            etr[mm][o] = t2;
        }
    }

    const float* emb = em + (size_t)b * TT * KK;

    // init: p = exp(S_0 - c), c = S_0[0]; lane j holds p[j]
    float s0i = start[j] + emb[j];
    float c = bcast(s0i, 0);
    float psc = ownj ? __expf(s0i - c) : 0.0f;

    pl[lane] = psc;                     // publish p for step 1

    // emission prefetch pipeline
    float pipe[PF];
    #pragma unroll
    for (int d = 0; d < PF; ++d) pipe[d] = emb[(size_t)(1 + d) * KK + j];

    const float* grp = pl + 12 * g;     // this lane's input-group slice
    const bool selB = (g == 1), selC = (g >= 2);
    float pcap = 0.f, ccap = 0.f;

    for (int t = 1; t + PF <= TT + 1; t += PF) {
        const bool tail = (t + PF > len);   // tail blocks renorm every step
        #pragma unroll
        for (int d = 0; d < PF; ++d) {
            const int tc = t + d;
            const bool renorm = (d == 0) || (d == 4) || tail;
            // capture pre-step state at t == len (state after len-1 steps)
            if (tc == len) { pcap = psc; ccap = c; }
            float e = __expf(pipe[d]);
            { int tt = tc + PF; tt = tt < TT ? tt : TT - 1;
              pipe[d] = emb[(size_t)tt * KK + j]; }
            // read own group's 12 p-values (written at end of prev step)
            float4 qa = *(const float4*)(grp);
            float4 qb = *(const float4*)(grp + 4);
            float4 qc = *(const float4*)(grp + 8);
            // p_prev[0] for renorm (lane 0's qa.x), wave-uniform
            float s0u = bcast(qa.x, 0);
            // partials over own 12 inputs for the 3 owned outputs
            v2f p2[6];
            p2[0] = mk2(qa.x, qa.y); p2[1] = mk2(qa.z, qa.w);
            p2[2] = mk2(qb.x, qb.y); p2[3] = mk2(qb.z, qb.w);
            p2[4] = mk2(qc.x, qc.y); p2[5] = mk2(qc.z, qc.w);
            v2f A0 = p2[0] * etr[0][0];
            v2f A1 = p2[0] * etr[0][1];
            v2f A2 = p2[0] * etr[0][2];
            #pragma unroll
            for (int mm = 1; mm < 6; ++mm) {
                A0 = __builtin_elementwise_fma(p2[mm], etr[mm][0], A0);
                A1 = __builtin_elementwise_fma(p2[mm], etr[mm][1], A1);
                A2 = __builtin_elementwise_fma(p2[mm], etr[mm][2], A2);
            }
            float h0 = A0.x + A0.y, h1 = A1.x + A1.y, h2 = A2.x + A2.y;
            // cross-group reduce (3 independent butterfly chains)
            float o0 = xred4(h0), o1 = xred4(h1), o2 = xred4(h2);
            // lane j's own output sits in slot g
            float sel = selB ? o1 : o0;
            sel       = selC ? o2 : sel;
            float scale = e;
            if (renorm) scale *= __builtin_amdgcn_rcpf(s0u);
            psc = sel * scale;
            if (renorm) c += __logf(s0u);
            pl[lane] = psc;             // publish for next step
        }
    }

    // log_z = ccap + log(sum_j pcap_j * exp(end_j))
    float v = ownj ? pcap * __expf(endt[j]) : 0.0f;
    #pragma unroll
    for (int off = 32; off >= 1; off >>= 1) v += __shfl_xor(v, off);

    // ---- fused gold-path score (mask is prefix: m[t] == (t < len)) ----
    const int* tgb = tags + b * TT;
    float sq = 0.f;
    for (int tt2 = lane; tt2 < TT; tt2 += 64) {
        if (tt2 >= 1 && tt2 < len) {
            int tp = tgb[tt2 - 1], tn = tgb[tt2];
            sq += trans[tp * KK + tn] + emb[(size_t)tt2 * KK + tn];
        }
    }
    #pragma unroll
    for (int off = 32; off >= 1; off >>= 1) sq += __shfl_xor(sq, off);

    if (lane == 0) {
        int t0 = tgb[0];
        ws[b]      = ccap + __logf(v);
        ws[BB + b] = sq + start[t0] + emb[t0] + endt[tgb[len - 1]];
    }
}

// ---------------- final mean reduction ----------------
__global__ __launch_bounds__(256) void crf_final(const float* __restrict__ ws,
                                                 float* __restrict__ out)
{
    __shared__ float red[256];
    float s = 0.f;
    for (int b = threadIdx.x; b < BB; b += 256) s += ws[b] - ws[BB + b];
    red[threadIdx.x] = s;
    __syncthreads();
    for (int off = 128; off > 0; off >>= 1) {
        if (threadIdx.x < off) red[threadIdx.x] += red[threadIdx.x + off];
        __syncthreads();
    }
    if (threadIdx.x == 0) out[0] = red[0] / (float)BB;
}

extern "C" void kernel_launch(void* const* d_in, const int* in_sizes, int n_in,
                              void* d_out, int out_size, void* d_ws, size_t ws_size,
                              hipStream_t stream) {
    const float* em    = (const float*)d_in[0];
    const int*   tags  = (const int*)d_in[1];
    const void*  mask  = d_in[2];
    const float* trans = (const float*)d_in[3];
    const float* start = (const float*)d_in[4];
    const float* endt  = (const float*)d_in[5];
    float* ws  = (float*)d_ws;
    float* out = (float*)d_out;

    crf_fwd  <<<BB, 64,  0, stream>>>(em, tags, mask, trans, start, endt, ws);
    crf_final<<<1,  256, 0, stream>>>(ws, out);
}

// Round 9
// 345.432 us; speedup vs baseline: 1.5988x; 1.0672x over previous
//
#include <hip/hip_runtime.h>
#include <stdint.h>

#define BB 512
#define TT 1024
#define KK 48
#define PF 8

typedef float v2f __attribute__((ext_vector_type(2)));
typedef unsigned u2u __attribute__((ext_vector_type(2)));

// mask may arrive as 1-byte bools (raw numpy) or as 4-byte words.
__device__ __forceinline__ int mask_at(const void* m, int idx, bool bytes) {
    return bytes ? (int)(((const uint8_t*)m)[idx] != 0)
                 : (int)(((const int*)m)[idx] != 0);
}

__device__ __forceinline__ float bcast(float v, int lane) {
    return __int_as_float(__builtin_amdgcn_readlane(__float_as_int(v), lane));
}

__device__ __forceinline__ v2f mk2(float x, float y) { v2f r; r.x = x; r.y = y; return r; }

// 4-way cross-group (16-lane rows) sum.
// R13: R12's __shfl_xor stages are ds_bpermute -> 2 serial DS-pipe hops
// (~130cy each) on the recurrence chain. gfx950 permlane*_swap are VALU
// (~5cy). With a=b=h, swap+add = pairwise row sums ((r0+r1),(r2+r3)) in all
// lanes; 32-swap+add finishes. Same add pairing as the shfl version ->
// bit-identical result. Builtins only (R10's hand-asm crashed); __has_builtin
// guard falls back to shfl (== R12) if absent.
__device__ __forceinline__ float xred4(float h) {
#if __has_builtin(__builtin_amdgcn_permlane16_swap) && __has_builtin(__builtin_amdgcn_permlane32_swap)
    u2u a = __builtin_amdgcn_permlane16_swap(__float_as_uint(h), __float_as_uint(h), false, false);
    float s = __uint_as_float(a[0]) + __uint_as_float(a[1]);
    u2u b = __builtin_amdgcn_permlane32_swap(__float_as_uint(s), __float_as_uint(s), false, false);
    return __uint_as_float(b[0]) + __uint_as_float(b[1]);
#else
    h += __shfl_xor(h, 16);
    h += __shfl_xor(h, 32);
    return h;
#endif
}

// ------------- forward algorithm, split-K(4x16), one row per wave ---------
// Structure (R12, ran correct): lane=(g,l): partials for outputs
// {l,l+16,l+32} over inputs {12g..12g+11}, cross-group reduce, lane j keeps
// its own output (slot o=g), scalar emission+renorm, publish via
// 1 ds_write_b32 + 3 float4 reads of the lane's 12-float group slice.
// R13 delta: VALU permlane reduce (kills 2 of 3 DS hops/step) + split FMA
// accumulators (chain depth 6 -> 3+1). 100% compiler-managed memory ops
// (R10/R11 asm-DS aborts; R12 style proven). Renorm schedule (d==0||d==4
// main, every-step tail) and t==len capture replicate R0 exactly.
__global__ __launch_bounds__(64, 1) void crf_fwd(
    const float* __restrict__ em, const int* __restrict__ tags,
    const void* __restrict__ mask, const float* __restrict__ trans,
    const float* __restrict__ start, const float* __restrict__ endt,
    float* __restrict__ ws)
{
    __shared__ __align__(16) float pl[64];   // 0..47 = p; 48..63 dummy

    const int b = blockIdx.x;
    const int lane = threadIdx.x;
    const int g = lane >> 4;          // input group 0..3
    const int l = lane & 15;
    const bool ownj = lane < KK;      // lane j<48 owns state j
    const int j = ownj ? lane : KK - 1;   // clamp for em loads

    const bool mb = (*(const int*)mask) == 0x01010101;

    // sequence length = popcount of prefix mask
    int cnt = 0;
    for (int t = lane; t < TT; t += 64) cnt += mask_at(mask, b * TT + t, mb);
    #pragma unroll
    for (int off = 32; off >= 1; off >>= 1) cnt += __shfl_xor(cnt, off);
    const int len = cnt;

    // E fragments: etr[mm][o] = (E[12g+2mm][16o+l], E[12g+2mm+1][16o+l])
    v2f etr[6][3];
    #pragma unroll
    for (int mm = 0; mm < 6; ++mm) {
        #pragma unroll
        for (int o = 0; o < 3; ++o) {
            const int i0 = 12 * g + 2 * mm;
            const int jo = 16 * o + l;
            v2f t2 = mk2(__expf(trans[i0 * KK + jo]),
                         __expf(trans[(i0 + 1) * KK + jo]));
            asm volatile("" : "+v"(t2));
            etr[mm][o] = t2;
        }
    }

    const float* emb = em + (size_t)b * TT * KK;

    // init: p = exp(S_0 - c), c = S_0[0]; lane j holds p[j]
    float s0i = start[j] + emb[j];
    float c = bcast(s0i, 0);
    float psc = ownj ? __expf(s0i - c) : 0.0f;

    pl[lane] = psc;                     // publish p for step 1

    // emission prefetch pipeline
    float pipe[PF];
    #pragma unroll
    for (int d = 0; d < PF; ++d) pipe[d] = emb[(size_t)(1 + d) * KK + j];

    const float* grp = pl + 12 * g;     // this lane's input-group slice
    const bool selB = (g == 1), selC = (g >= 2);
    float pcap = 0.f, ccap = 0.f;

    for (int t = 1; t + PF <= TT + 1; t += PF) {
        const bool tail = (t + PF > len);   // tail blocks renorm every step
        #pragma unroll
        for (int d = 0; d < PF; ++d) {
            const int tc = t + d;
            const bool renorm = (d == 0) || (d == 4) || tail;
            // capture pre-step state at t == len (state after len-1 steps)
            if (tc == len) { pcap = psc; ccap = c; }
            float e = __expf(pipe[d]);
            { int tt = tc + PF; tt = tt < TT ? tt : TT - 1;
              pipe[d] = emb[(size_t)tt * KK + j]; }
            // read own group's 12 p-values (written at end of prev step)
            float4 qa = *(const float4*)(grp);
            float4 qb = *(const float4*)(grp + 4);
            float4 qc = *(const float4*)(grp + 8);
            // p_prev[0] for renorm (lane 0's qa.x), wave-uniform
            float s0u = bcast(qa.x, 0);
            // partials over own 12 inputs for the 3 owned outputs
            // (two half-chains per output: depth 3 + 1 combine)
            v2f p2[6];
            p2[0] = mk2(qa.x, qa.y); p2[1] = mk2(qa.z, qa.w);
            p2[2] = mk2(qb.x, qb.y); p2[3] = mk2(qb.z, qb.w);
            p2[4] = mk2(qc.x, qc.y); p2[5] = mk2(qc.z, qc.w);
            v2f A0a = p2[0] * etr[0][0];
            v2f A1a = p2[0] * etr[0][1];
            v2f A2a = p2[0] * etr[0][2];
            v2f A0b = p2[3] * etr[3][0];
            v2f A1b = p2[3] * etr[3][1];
            v2f A2b = p2[3] * etr[3][2];
            #pragma unroll
            for (int mm = 1; mm < 3; ++mm) {
                A0a = __builtin_elementwise_fma(p2[mm], etr[mm][0], A0a);
                A1a = __builtin_elementwise_fma(p2[mm], etr[mm][1], A1a);
                A2a = __builtin_elementwise_fma(p2[mm], etr[mm][2], A2a);
                A0b = __builtin_elementwise_fma(p2[mm + 3], etr[mm + 3][0], A0b);
                A1b = __builtin_elementwise_fma(p2[mm + 3], etr[mm + 3][1], A1b);
                A2b = __builtin_elementwise_fma(p2[mm + 3], etr[mm + 3][2], A2b);
            }
            v2f A0 = A0a + A0b, A1 = A1a + A1b, A2 = A2a + A2b;
            float h0 = A0.x + A0.y, h1 = A1.x + A1.y, h2 = A2.x + A2.y;
            // cross-group reduce: VALU permlane swaps (3 independent chains)
            float o0 = xred4(h0), o1 = xred4(h1), o2 = xred4(h2);
            // lane j's own output sits in slot g
            float sel = selB ? o1 : o0;
            sel       = selC ? o2 : sel;
            float scale = e;
            if (renorm) scale *= __builtin_amdgcn_rcpf(s0u);
            psc = sel * scale;
            if (renorm) c += __logf(s0u);
            pl[lane] = psc;             // publish for next step
        }
    }

    // log_z = ccap + log(sum_j pcap_j * exp(end_j))
    float v = ownj ? pcap * __expf(endt[j]) : 0.0f;
    #pragma unroll
    for (int off = 32; off >= 1; off >>= 1) v += __shfl_xor(v, off);

    // ---- fused gold-path score (mask is prefix: m[t] == (t < len)) ----
    const int* tgb = tags + b * TT;
    float sq = 0.f;
    for (int tt2 = lane; tt2 < TT; tt2 += 64) {
        if (tt2 >= 1 && tt2 < len) {
            int tp = tgb[tt2 - 1], tn = tgb[tt2];
            sq += trans[tp * KK + tn] + emb[(size_t)tt2 * KK + tn];
        }
    }
    #pragma unroll
    for (int off = 32; off >= 1; off >>= 1) sq += __shfl_xor(sq, off);

    if (lane == 0) {
        int t0 = tgb[0];
        ws[b]      = ccap + __logf(v);
        ws[BB + b] = sq + start[t0] + emb[t0] + endt[tgb[len - 1]];
    }
}

// ---------------- final mean reduction ----------------
__global__ __launch_bounds__(256) void crf_final(const float* __restrict__ ws,
                                                 float* __restrict__ out)
{
    __shared__ float red[256];
    float s = 0.f;
    for (int b = threadIdx.x; b < BB; b += 256) s += ws[b] - ws[BB + b];
    red[threadIdx.x] = s;
    __syncthreads();
    for (int off = 128; off > 0; off >>= 1) {
        if (threadIdx.x < off) red[threadIdx.x] += red[threadIdx.x + off];
        __syncthreads();
    }
    if (threadIdx.x == 0) out[0] = red[0] / (float)BB;
}

extern "C" void kernel_launch(void* const* d_in, const int* in_sizes, int n_in,
                              void* d_out, int out_size, void* d_ws, size_t ws_size,
                              hipStream_t stream) {
    const float* em    = (const float*)d_in[0];
    const int*   tags  = (const int*)d_in[1];
    const void*  mask  = d_in[2];
    const float* trans = (const float*)d_in[3];
    const float* start = (const float*)d_in[4];
    const float* endt  = (const float*)d_in[5];
    float* ws  = (float*)d_ws;
    float* out = (float*)d_out;

    crf_fwd  <<<BB, 64,  0, stream>>>(em, tags, mask, trans, start, endt, ws);
    crf_final<<<1,  256, 0, stream>>>(ws, out);
}